// Round 1
// 259.778 us; speedup vs baseline: 1.0576x; 1.0576x over previous
//
#include <hip/hip_runtime.h>
#include <hip/hip_bf16.h>
#include <cstdint>

#define CIN 128
#define NH 8
#define CH 32
#define LDQ16 1024   // qkvg row stride in shorts: [q 256|k 256|v 256|g 256]

typedef short bf16x8 __attribute__((ext_vector_type(8)));
typedef short bf16x4 __attribute__((ext_vector_type(4)));
typedef float f32x4 __attribute__((ext_vector_type(4)));

__device__ __forceinline__ short f2bf(float f) {
  union { float f; unsigned u; } v; v.f = f;
  unsigned r = (v.u + 0x7FFFu + ((v.u >> 16) & 1u)) >> 16;   // RNE
  return (short)r;
}
__device__ __forceinline__ float bf2f(short s) {
  union { unsigned u; float f; } v; v.u = ((unsigned)(unsigned short)s) << 16;
  return v.f;
}
__device__ __forceinline__ unsigned pk2bf(float a, float b) {
  union { __hip_bfloat162 h; unsigned u; } cv;
  cv.h = __float22bfloat162_rn(make_float2(a, b));
  return cv.u;
}

// ---------------- merged prep: x->bf16 | weights->bf16 [n][k] | mask detect ----------------
// blocks 0..4095: xb ; 4096..4159: WT/WoT ; 4160: detect_mask
__global__ __launch_bounds__(256) void prep(
    const float* __restrict__ x,
    const float* __restrict__ Wq, const float* __restrict__ Wk,
    const float* __restrict__ Wv, const float* __restrict__ Wg,
    const float* __restrict__ Wo,
    const uint4* __restrict__ mask,
    short* __restrict__ xb, short* __restrict__ WT, short* __restrict__ WoT,
    unsigned int* __restrict__ flag)
{
  __shared__ int viol;
  const int b = blockIdx.x;
  if (b < 4096) {
    int base = (b * 256 + threadIdx.x) * 8;
    float4 a = *(const float4*)(x + base);
    float4 c = *(const float4*)(x + base + 4);
    bf16x8 r;
    r[0] = f2bf(a.x); r[1] = f2bf(a.y); r[2] = f2bf(a.z); r[3] = f2bf(a.w);
    r[4] = f2bf(c.x); r[5] = f2bf(c.y); r[6] = f2bf(c.z); r[7] = f2bf(c.w);
    *(bf16x8*)(xb + base) = r;
  } else if (b < 4160) {
    const float qscale = 0.17677669529663689f;  // 1/sqrt(32)
    int bb = b - 4096;
#pragma unroll
    for (int e = 0; e < 10; ++e) {
      int o = bb * 2560 + e * 256 + threadIdx.x;
      if (o < 131072) {
        int n = o >> 7, k = o & 127;
        int seg = n >> 8, nn = n & 255;
        const float* W = (seg == 0) ? Wq : (seg == 1) ? Wk : (seg == 2) ? Wv : Wg;
        float v = W[k * 256 + nn];
        if (seg == 0) v *= qscale;
        WT[o] = f2bf(v);
      } else {
        int o2 = o - 131072;
        int n = o2 >> 8, k = o2 & 255;
        WoT[o2] = f2bf(Wo[k * 128 + n]);
      }
    }
  } else {
    if (threadIdx.x == 0) viol = 0;
    __syncthreads();
    int v = 0;
#pragma unroll
    for (int j = 0; j < 16; ++j) {
      uint4 w = mask[j * 256 + threadIdx.x];
      v |= (w.x > 1u) | (w.y > 1u) | (w.z > 1u) | (w.w > 1u);
    }
    if (v) atomicOr(&viol, 1);
    __syncthreads();
    if (threadIdx.x == 0) *flag = viol ? 0u : 1u;
  }
}

// ---------------- QKVG projection, bf16 MFMA ----------------
__global__ __launch_bounds__(256) void proj_qkvg(
    const short* __restrict__ xb, const short* __restrict__ WT,
    const float* __restrict__ bg, short* __restrict__ qkvg)
{
  __shared__ short Al[64 * 136];
  __shared__ short Bl[128 * 136];
  const int tid = threadIdx.x;
  const int lane = tid & 63, w = tid >> 6;
  const int g = lane >> 4, c16 = lane & 15;
  const int wr = w & 1, wc = w >> 1;
  const int n0 = blockIdx.x * 128;
  const int row0 = blockIdx.y * 64;

  {
    const short* src = xb + (size_t)row0 * 128;
#pragma unroll
    for (int ch = 0; ch < 4; ++ch) {
      int c = ch * 256 + tid;
      int r = c >> 4, kc = c & 15;
      *(bf16x8*)&Al[r * 136 + kc * 8] = *(const bf16x8*)(src + r * 128 + kc * 8);
    }
    const short* wsrc = WT + (size_t)n0 * 128;
#pragma unroll
    for (int ch = 0; ch < 8; ++ch) {
      int c = ch * 256 + tid;
      int r = c >> 4, kc = c & 15;
      *(bf16x8*)&Bl[r * 136 + kc * 8] = *(const bf16x8*)(wsrc + r * 128 + kc * 8);
    }
  }
  __syncthreads();

  f32x4 acc[2][4];
#pragma unroll
  for (int rt = 0; rt < 2; ++rt)
#pragma unroll
    for (int ct = 0; ct < 4; ++ct) acc[rt][ct] = (f32x4){0.f, 0.f, 0.f, 0.f};

#pragma unroll
  for (int kk = 0; kk < 4; ++kk) {
    bf16x8 af[2], bfr[4];
#pragma unroll
    for (int rt = 0; rt < 2; ++rt)
      af[rt] = *(const bf16x8*)&Al[(wr * 32 + rt * 16 + c16) * 136 + kk * 32 + g * 8];
#pragma unroll
    for (int ct = 0; ct < 4; ++ct)
      bfr[ct] = *(const bf16x8*)&Bl[(wc * 64 + ct * 16 + c16) * 136 + kk * 32 + g * 8];
#pragma unroll
    for (int rt = 0; rt < 2; ++rt)
#pragma unroll
      for (int ct = 0; ct < 4; ++ct)
        acc[rt][ct] = __builtin_amdgcn_mfma_f32_16x16x32_bf16(af[rt], bfr[ct], acc[rt][ct], 0, 0, 0);
  }

  const int seg3 = (n0 >= 768);
  float bgv[4];
  if (seg3) {
#pragma unroll
    for (int ct = 0; ct < 4; ++ct)
      bgv[ct] = bg[n0 - 768 + wc * 64 + ct * 16 + c16];
  }
#pragma unroll
  for (int rt = 0; rt < 2; ++rt)
#pragma unroll
    for (int ct = 0; ct < 4; ++ct) {
      int col = n0 + wc * 64 + ct * 16 + c16;
#pragma unroll
      for (int i = 0; i < 4; ++i) {
        int row = row0 + wr * 32 + rt * 16 + g * 4 + i;
        float v = acc[rt][ct][i];
        if (seg3) v = 1.f / (1.f + __expf(-(v + bgv[ct])));
        qkvg[(size_t)row * LDQ16 + col] = f2bf(v);
      }
    }
}

// ---------------- MFMA flash attention, S^T formulation, single-pass ----------------
// S^T = K.Q^T via mfma(kf, qf): thread holds 4 consecutive KEYS at fixed q.
// PV: 16x16x16 MFMA whose A-frag layout (row=c16, k=g*4..+3) EXACTLY matches the
// S^T output fragment -> P stays in registers, no LDS round-trip, pL deleted.
// LDS shorts (38432 B total -> 4 blocks/CU):
//   kL@0 [256key][40]; vTd@10240 [32c][132]dw; lL@18688 (4w x 64 f32); mask@19200.
__global__ __launch_bounds__(256, 4) void attn(
    short* __restrict__ qkvg, const float* __restrict__ bias,
    const void* __restrict__ maskraw, const unsigned int* __restrict__ flagp)
{
  __shared__ __align__(16) short lds16[19216];
  const int tid = threadIdx.x;
  const int h = blockIdx.x;
  const int srow = blockIdx.y;
  const int lane = tid & 63, w = tid >> 6;
  const int g = lane >> 4, c16 = lane & 15;
  short* rowbase = qkvg + (size_t)srow * (256 * LDQ16);
  unsigned int* vTd = (unsigned int*)&lds16[10240];
  float* lL = (float*)&lds16[18688];

  // ---- mask row -> 8x u32 bits ----
  const unsigned int fl = *flagp;
  int mv = fl ? ((const int*)maskraw)[srow * 256 + tid]
              : (int)((const unsigned char*)maskraw)[srow * 256 + tid];
  unsigned long long bb = __ballot(mv != 0);
  unsigned int* scratch = (unsigned int*)&lds16[19200];
  if (lane == 0) {
    scratch[w * 2 + 0] = (unsigned int)bb;
    scratch[w * 2 + 1] = (unsigned int)(bb >> 32);
  }

  // ---- stage k -> kL[key][c] (b128), v -> vTd packed key-pairs (b32) ----
#pragma unroll
  for (int it = 0; it < 2; ++it) {
    int c = it * 256 + tid;          // keypair(128) x cquad(4)
    int kp = c >> 2, cv = c & 3;
    const short* p0 = rowbase + (size_t)(2 * kp) * LDQ16 + 256 + h * CH + cv * 8;
    bf16x8 k0 = *(const bf16x8*)p0;
    bf16x8 k1 = *(const bf16x8*)(p0 + LDQ16);
    bf16x8 v0 = *(const bf16x8*)(p0 + 256);
    bf16x8 v1 = *(const bf16x8*)(p0 + LDQ16 + 256);
    *(bf16x8*)&lds16[(2 * kp) * 40 + cv * 8] = k0;
    *(bf16x8*)&lds16[(2 * kp + 1) * 40 + cv * 8] = k1;
#pragma unroll
    for (int j = 0; j < 8; ++j)
      vTd[(cv * 8 + j) * 132 + kp] =
          ((unsigned)(unsigned short)v0[j]) | (((unsigned)(unsigned short)v1[j]) << 16);
  }

  // ---- q B-frags direct from global bf16 (B[k=chan][n=q] wants [q][chan] layout) ----
  const int qb = w * 64;
  bf16x8 qf[4];
#pragma unroll
  for (int qt = 0; qt < 4; ++qt)
    qf[qt] = *(const bf16x8*)(rowbase + (size_t)(qb + qt * 16 + c16) * LDQ16 + h * CH + g * 8);

  __syncthreads();   // only barrier: staging + mask visible

  unsigned int mb[8];
#pragma unroll
  for (int j = 0; j < 8; ++j) mb[j] = scratch[j];

  const f32x4 zero4 = {0.f, 0.f, 0.f, 0.f};
  float l_[4] = {0.f, 0.f, 0.f, 0.f};
  f32x4 O[4][2];
#pragma unroll
  for (int qt = 0; qt < 4; ++qt) { O[qt][0] = zero4; O[qt][1] = zero4; }

  const float* bh = bias + (size_t)h * 65536;

  for (int ch = 0; ch < 8; ++ch) {
    // prefetch bias: thread covers keys ch*32+kt*16+g*4.. (4 consecutive) at q=qt*16+c16
    float4 bb4[2][4];
#pragma unroll
    for (int kt = 0; kt < 2; ++kt)
#pragma unroll
      for (int qt = 0; qt < 4; ++qt)
        bb4[kt][qt] = *(const float4*)(bh + (size_t)(qb + qt * 16 + c16) * 256 +
                                       ch * 32 + kt * 16 + g * 4);

#pragma unroll
    for (int kt = 0; kt < 2; ++kt) {
      // A-frag K: row=key ch*32+kt*16+c16, k-elems = chans g*8..+7
      bf16x8 kf = *(const bf16x8*)&lds16[(ch * 32 + kt * 16 + c16) * 40 + g * 8];
      // PV B-frags (16x16x16): B[k=key][n=chan]: lane holds keys g*4..+3 at chan c16 / 16+c16.
      // vTd dword kp packs {V[2kp],V[2kp+1]} -> b64 at kp = ch*16+kt*8+g*2 gives keys
      // ch*32+kt*16+g*4+{0..3} in ascending element order.
      bf16x4 vlo, vhi;
      {
        union { unsigned u[2]; bf16x4 v; } t0, t1;
        const unsigned* plo = &vTd[(size_t)c16 * 132 + ch * 16 + kt * 8 + g * 2];
        const unsigned* phi = &vTd[(size_t)(16 + c16) * 132 + ch * 16 + kt * 8 + g * 2];
        t0.u[0] = plo[0]; t0.u[1] = plo[1];
        t1.u[0] = phi[0]; t1.u[1] = phi[1];
        vlo = t0.v; vhi = t1.v;
      }
      const unsigned nib = (mb[ch] >> (kt * 16 + g * 4)) & 0xFu;
      float em[4];
#pragma unroll
      for (int i = 0; i < 4; ++i) em[i] = ((nib >> i) & 1u) ? 1.f : 0.f;
#pragma unroll
      for (int qt = 0; qt < 4; ++qt) {
        f32x4 S = __builtin_amdgcn_mfma_f32_16x16x32_bf16(kf, qf[qt], zero4, 0, 0, 0);
        float p0 = em[0] * __expf(fminf(S[0] + bb4[kt][qt].x, 85.f));
        float p1 = em[1] * __expf(fminf(S[1] + bb4[kt][qt].y, 85.f));
        float p2 = em[2] * __expf(fminf(S[2] + bb4[kt][qt].z, 85.f));
        float p3 = em[3] * __expf(fminf(S[3] + bb4[kt][qt].w, 85.f));
        l_[qt] += (p0 + p1) + (p2 + p3);
        // P A-frag for 16x16x16: lane(g,c16) holds P[q=c16][keys g*4..+3] -- exactly p0..p3.
        union { unsigned u[2]; bf16x4 v; } pu;
        pu.u[0] = pk2bf(p0, p1);
        pu.u[1] = pk2bf(p2, p3);
        O[qt][0] = __builtin_amdgcn_mfma_f32_16x16x16bf16_1k(pu.v, vlo, O[qt][0], 0, 0, 0);
        O[qt][1] = __builtin_amdgcn_mfma_f32_16x16x16bf16_1k(pu.v, vhi, O[qt][1], 0, 0, 0);
      }
    }
  }

  // ---- l reduction: sum over 4 g-groups; park per-wave in lL ----
#pragma unroll
  for (int qt = 0; qt < 4; ++qt) {
    float v = l_[qt];
    v += __shfl_xor(v, 16);
    v += __shfl_xor(v, 32);
    if (lane < 16) lL[w * 64 + qt * 16 + c16] = v;
  }

  // ---- epilogue: O/l * gate -> q slot (bf16) ----
#pragma unroll
  for (int qt = 0; qt < 4; ++qt)
#pragma unroll
    for (int i = 0; i < 4; ++i) {
      float l = lL[w * 64 + qt * 16 + g * 4 + i];
      float inv = 1.f / l;
      short* orow = rowbase + (size_t)(qb + qt * 16 + g * 4 + i) * LDQ16;
#pragma unroll
      for (int half = 0; half < 2; ++half) {
        int c = half * 16 + c16;
        float gv = bf2f(orow[768 + h * CH + c]);
        orow[h * CH + c] = f2bf(O[qt][half][i] * inv * gv);
      }
    }
}

// ---------------- output projection: out = oG @ Wo + bo, bf16 MFMA ----------------
__global__ __launch_bounds__(256) void out_proj(
    const short* __restrict__ og, const short* __restrict__ WoT,
    const float* __restrict__ bo, float* __restrict__ out)
{
  __shared__ short Al[64 * 136];
  __shared__ short Bl[128 * 136];
  const int tid = threadIdx.x;
  const int lane = tid & 63, w = tid >> 6;
  const int g = lane >> 4, c16 = lane & 15;
  const int wr = w & 1, wc = w >> 1;
  const int row0 = blockIdx.x * 64;

  f32x4 acc[2][4];
#pragma unroll
  for (int rt = 0; rt < 2; ++rt)
#pragma unroll
    for (int ct = 0; ct < 4; ++ct) acc[rt][ct] = (f32x4){0.f, 0.f, 0.f, 0.f};

  for (int kk0 = 0; kk0 < 256; kk0 += 128) {
#pragma unroll
    for (int ch = 0; ch < 4; ++ch) {
      int c = ch * 256 + tid;
      int r = c >> 4, kc = c & 15;
      *(bf16x8*)&Al[r * 136 + kc * 8] =
          *(const bf16x8*)(og + (size_t)(row0 + r) * LDQ16 + kk0 + kc * 8);
    }
#pragma unroll
    for (int ch = 0; ch < 8; ++ch) {
      int c = ch * 256 + tid;
      int r = c >> 4, kc = c & 15;
      *(bf16x8*)&Bl[r * 136 + kc * 8] =
          *(const bf16x8*)(WoT + (size_t)r * 256 + kk0 + kc * 8);
    }
    __syncthreads();
#pragma unroll
    for (int kk = 0; kk < 4; ++kk) {
      bf16x8 af[2], bfr[4];
#pragma unroll
      for (int rt = 0; rt < 2; ++rt)
        af[rt] = *(const bf16x8*)&Al[(wr * 32 + rt * 16 + c16) * 136 + kk * 32 + g * 8];
#pragma unroll
      for (int ct = 0; ct < 4; ++ct)
        bfr[ct] = *(const bf16x8*)&Bl[(wc * 64 + ct * 16 + c16) * 136 + kk * 32 + g * 8];
#pragma unroll
      for (int rt = 0; rt < 2; ++rt)
#pragma unroll
        for (int ct = 0; ct < 4; ++ct)
          acc[rt][ct] = __builtin_amdgcn_mfma_f32_16x16x32_bf16(af[rt], bfr[ct], acc[rt][ct], 0, 0, 0);
    }
    __syncthreads();
  }

#pragma unroll
  for (int rt = 0; rt < 2; ++rt)
#pragma unroll
    for (int ct = 0; ct < 4; ++ct) {
      int col = wc * 64 + ct * 16 + c16;
      float bv = bo[col];
#pragma unroll
      for (int i = 0; i < 4; ++i) {
        int row = row0 + wr * 32 + rt * 16 + g * 4 + i;
        out[(size_t)row * CIN + col] = acc[rt][ct][i] + bv;
      }
    }
}

extern "C" void kernel_launch(void* const* d_in, const int* in_sizes, int n_in,
                              void* d_out, int out_size, void* d_ws, size_t ws_size,
                              hipStream_t stream) {
  const float* x    = (const float*)d_in[0];
  const float* bias = (const float*)d_in[1];
  const void*  mask = d_in[2];
  const float* Wq   = (const float*)d_in[3];
  const float* Wk   = (const float*)d_in[4];
  const float* Wv   = (const float*)d_in[5];
  const float* Wo   = (const float*)d_in[6];
  const float* bo   = (const float*)d_in[7];
  const float* Wg   = (const float*)d_in[8];
  const float* bg   = (const float*)d_in[9];
  float* out = (float*)d_out;

  // ws: [flag 256B][WT 256KB][WoT 64KB][xb 16MB][qkvg bf16 128MB]
  unsigned int* flag = (unsigned int*)d_ws;
  short* WT   = (short*)((char*)d_ws + 256);
  short* WoT  = WT + 131072;
  short* xb   = WoT + 32768;
  short* qkvg = xb + (size_t)65536 * 128;

  prep<<<4161, 256, 0, stream>>>(x, Wq, Wk, Wv, Wg, Wo, (const uint4*)mask,
                                 xb, WT, WoT, flag);
  proj_qkvg<<<dim3(8, 1024), 256, 0, stream>>>(xb, WT, bg, qkvg);
  attn<<<dim3(NH, 256), 256, 0, stream>>>(qkvg, bias, mask, flag);
  out_proj<<<1024, 256, 0, stream>>>(qkvg, WoT, bo, out);
}